// Round 1
// baseline (385.584 us; speedup 1.0000x reference)
//
#include <hip/hip_runtime.h>
#include <hip/hip_bf16.h>

// Problem constants
#define Bsz 8192
#define Isz 1024
#define Hsz 1024
#define Ksz 2048   // I + H (concatenated GEMM K)
#define Nsz 4096   // 4*H  (stacked gates)

// GEMM tiling (m97 structure)
#define BM 128
#define BN 128
#define BK 32

typedef __attribute__((ext_vector_type(8))) short bf16x8;  // 8 bf16 = 4 VGPRs
typedef __attribute__((ext_vector_type(4))) float f32x4;

__device__ __forceinline__ void async_copy16(const void* g, void* l) {
  __builtin_amdgcn_global_load_lds(
      (const __attribute__((address_space(1))) void*)g,
      (__attribute__((address_space(3))) void*)l, 16, 0, 0);
}

__device__ __forceinline__ float sigmoid_f(float x) {
  return 1.0f / (1.0f + __expf(-x));
}
__device__ __forceinline__ float tanh_f(float x) {
  x = fminf(15.0f, fmaxf(-15.0f, x));   // avoid inf/inf -> NaN
  const float e = __expf(-2.0f * x);
  return (1.0f - e) / (1.0f + e);
}

// ---------------------------------------------------------------------------
// Prep: build bf16 A=[x|h] (8192x2048), gate-interleaved bf16 W' (4096x2048)
// with W'[4*hh+g][k] = (k<I ? Wx : Wh)[g*H+hh][k'], and bsum[4*hh+g]=bx+bh.
// ---------------------------------------------------------------------------
__global__ __launch_bounds__(256) void prep_kernel(
    const float* __restrict__ x, const float* __restrict__ h,
    const float* __restrict__ Wx, const float* __restrict__ Wh,
    const float* __restrict__ bx, const float* __restrict__ bh,
    __hip_bfloat16* __restrict__ Abf, __hip_bfloat16* __restrict__ Wbf,
    float* __restrict__ bsum) {
  const int idx = blockIdx.x * 256 + threadIdx.x;
  const int ACH = (Bsz * Ksz) / 4;  // 4,194,304 float4 chunks for A

  if (idx < ACH) {
    const int b = idx >> 9;            // row (2048 elems = 512 chunks/row)
    const int k = (idx & 511) << 2;    // col
    const float* src = (k < Isz) ? (x + (size_t)b * Isz + k)
                                 : (h + (size_t)b * Hsz + (k - Isz));
    const float4 v = *(const float4*)src;
    __hip_bfloat16 t[4] = {__float2bfloat16(v.x), __float2bfloat16(v.y),
                           __float2bfloat16(v.z), __float2bfloat16(v.w)};
    *(ushort4*)(Abf + (size_t)b * Ksz + k) = *(const ushort4*)t;
  } else {
    const int t2 = idx - ACH;          // 2,097,152 chunks for W'
    const int r = t2 >> 9;             // permuted row 4*hh+g
    const int k = (t2 & 511) << 2;
    const int hh = r >> 2, g = r & 3;
    const float* src = (k < Isz) ? (Wx + (size_t)(g * Hsz + hh) * Isz + k)
                                 : (Wh + (size_t)(g * Hsz + hh) * Hsz + (k - Isz));
    const float4 v = *(const float4*)src;
    __hip_bfloat16 t[4] = {__float2bfloat16(v.x), __float2bfloat16(v.y),
                           __float2bfloat16(v.z), __float2bfloat16(v.w)};
    *(ushort4*)(Wbf + (size_t)r * Ksz + k) = *(const ushort4*)t;
  }
  if (idx < Nsz) {
    const int hh = idx >> 2, g = idx & 3;
    bsum[idx] = bx[g * Hsz + hh] + bh[g * Hsz + hh];
  }
}

// ---------------------------------------------------------------------------
// GEMM (A·W'^T) + fused LSTM epilogue.
// m97 structure: 128x128 block tile, BK=32, global_load_lds width=16,
// 4 waves in 2x2, each wave 4x4 grid of 16x16x32 bf16 MFMA.
// C/D layout: col = lane&15, row = (lane>>4)*4 + reg.
// Epilogue: 4x4 reg transpose (shfl_xor 1,2) -> lane holds i,f,o,g of one row.
// ---------------------------------------------------------------------------
__global__ __launch_bounds__(256) void lstm_gemm_kernel(
    const __hip_bfloat16* __restrict__ A,   // [8192][2048]
    const __hip_bfloat16* __restrict__ W,   // [4096][2048] gate-interleaved
    const float* __restrict__ bsum,         // [4096] gate-interleaved
    const float* __restrict__ c_prev,       // [8192][1024]
    float* __restrict__ c_out,              // [8192][1024]
    float* __restrict__ h_out) {            // [8192][1024]
  __shared__ __hip_bfloat16 As[BM * BK];  // 8 KB
  __shared__ __hip_bfloat16 Bs[BN * BK];  // 8 KB

  const int tid = threadIdx.x;
  const int lane = tid & 63;
  const int wave = tid >> 6;
  const int wm = wave & 1;
  const int wn = wave >> 1;
  const int row0 = blockIdx.x * BM;
  const int col0 = blockIdx.y * BN;

  const __hip_bfloat16* Ag = A + (size_t)row0 * Ksz;
  const __hip_bfloat16* Wg = W + (size_t)col0 * Ksz;

  // staging: chunk c covers LDS bytes [c*16, c*16+16); row=c>>2, col=(c&3)*8
  const int c0 = tid, c1 = tid + 256;
  const int ar0 = c0 >> 2, ak0 = (c0 & 3) * 8;
  const int ar1 = c1 >> 2, ak1 = (c1 & 3) * 8;

  f32x4 acc[4][4] = {};

  const int q = lane >> 4;    // quad
  const int cl = lane & 15;   // col within 16-wide tile

  for (int kt = 0; kt < Ksz; kt += BK) {
    __syncthreads();  // prior iteration's ds_reads complete before overwrite
    async_copy16(Ag + (size_t)ar0 * Ksz + kt + ak0, (char*)As + c0 * 16);
    async_copy16(Ag + (size_t)ar1 * Ksz + kt + ak1, (char*)As + c1 * 16);
    async_copy16(Wg + (size_t)ar0 * Ksz + kt + ak0, (char*)Bs + c0 * 16);
    async_copy16(Wg + (size_t)ar1 * Ksz + kt + ak1, (char*)Bs + c1 * 16);
    __syncthreads();  // vmcnt(0) drain before s_barrier covers the DMA

    bf16x8 af[4], bfr[4];
#pragma unroll
    for (int i = 0; i < 4; i++)
      af[i] = *(const bf16x8*)(As + (wm * 64 + i * 16 + cl) * BK + q * 8);
#pragma unroll
    for (int j = 0; j < 4; j++)
      bfr[j] = *(const bf16x8*)(Bs + (wn * 64 + j * 16 + cl) * BK + q * 8);
#pragma unroll
    for (int i = 0; i < 4; i++)
#pragma unroll
      for (int j = 0; j < 4; j++)
        acc[i][j] = __builtin_amdgcn_mfma_f32_16x16x32_bf16(af[i], bfr[j],
                                                            acc[i][j], 0, 0, 0);
  }

  // ---- fused LSTM epilogue ----
  const int s = cl & 3;     // gate slot of this lane; becomes its row offset
  const int hq = cl >> 2;   // h-index offset within this 16-col tile
#pragma unroll
  for (int j = 0; j < 4; j++) {
    const int coltile = col0 + wn * 64 + j * 16;
    const float bj = bsum[coltile + cl];
    const int hidx = (coltile >> 2) + hq;
#pragma unroll
    for (int i = 0; i < 4; i++) {
      float v[4], a1[4], a2[4];
#pragma unroll
      for (int r = 0; r < 4; r++) v[r] = acc[i][j][r] + bj;
      // 4x4 transpose across lane-low-2-bits x reg-index
#pragma unroll
      for (int r = 0; r < 4; r++) {
        const float t = __shfl_xor(v[r ^ 1], 1);
        a1[r] = ((r ^ s) & 1) ? t : v[r];
      }
#pragma unroll
      for (int r = 0; r < 4; r++) {
        const float t = __shfl_xor(a1[r ^ 2], 2);
        a2[r] = ((r ^ s) & 2) ? t : a1[r];
      }
      // a2[g] = gate g (0:i 1:f 2:o 3:g) for row below, h = hidx
      const int row = row0 + wm * 64 + i * 16 + q * 4 + s;
      const float ig = sigmoid_f(a2[0]);
      const float fg = sigmoid_f(a2[1]);
      const float og = sigmoid_f(a2[2]);
      const float gg = tanh_f(a2[3]);
      const size_t off = (size_t)row * Hsz + hidx;
      const float cn = fg * c_prev[off] + ig * gg;
      c_out[off] = cn;
      h_out[off] = og * tanh_f(cn);
    }
  }
}

extern "C" void kernel_launch(void* const* d_in, const int* in_sizes, int n_in,
                              void* d_out, int out_size, void* d_ws,
                              size_t ws_size, hipStream_t stream) {
  (void)in_sizes; (void)n_in; (void)out_size; (void)ws_size;
  const float* x  = (const float*)d_in[0];
  const float* cp = (const float*)d_in[1];
  const float* hp = (const float*)d_in[2];
  const float* Wx = (const float*)d_in[3];
  const float* bx = (const float*)d_in[4];
  const float* Wh = (const float*)d_in[5];
  const float* bh = (const float*)d_in[6];

  __hip_bfloat16* Abf = (__hip_bfloat16*)d_ws;            // 32 MB
  __hip_bfloat16* Wbf = Abf + (size_t)Bsz * Ksz;          // 16 MB
  float* bsum = (float*)(Wbf + (size_t)Nsz * Ksz);        // 16 KB

  float* c_out = (float*)d_out;
  float* h_out = c_out + (size_t)Bsz * Hsz;

  const int total_chunks = (Bsz * Ksz) / 4 + (Nsz * Ksz) / 4;  // 6,291,456
  prep_kernel<<<total_chunks / 256, 256, 0, stream>>>(x, hp, Wx, Wh, bx, bh,
                                                      Abf, Wbf, bsum);
  dim3 grid(Bsz / BM, Nsz / BN);  // 64 x 32
  lstm_gemm_kernel<<<grid, 256, 0, stream>>>(Abf, Wbf, bsum, cp, c_out, h_out);
}

// Round 2
// 340.902 us; speedup vs baseline: 1.1311x; 1.1311x over previous
//
#include <hip/hip_runtime.h>
#include <hip/hip_bf16.h>

// Problem constants
#define Bsz 8192
#define Isz 1024
#define Hsz 1024
#define Ksz 2048   // I + H (concatenated GEMM K)
#define Nsz 4096   // 4*H  (stacked gates)

// GEMM tiling (m97 structure)
#define BM 128
#define BN 128
#define BK 32

typedef __attribute__((ext_vector_type(8))) short bf16x8;  // 8 bf16 = 4 VGPRs
typedef __attribute__((ext_vector_type(4))) float f32x4;
typedef __attribute__((ext_vector_type(8))) unsigned short ushort8;

__device__ __forceinline__ void async_copy16(const void* g, void* l) {
  __builtin_amdgcn_global_load_lds(
      (const __attribute__((address_space(1))) void*)g,
      (__attribute__((address_space(3))) void*)l, 16, 0, 0);
}

__device__ __forceinline__ float sigmoid_f(float x) {
  return 1.0f / (1.0f + __expf(-x));
}
__device__ __forceinline__ float tanh_f(float x) {
  x = fminf(15.0f, fmaxf(-15.0f, x));   // avoid inf/inf -> NaN
  const float e = __expf(-2.0f * x);
  return (1.0f - e) / (1.0f + e);
}

__device__ __forceinline__ ushort8 cvt8(const float* s) {
  ushort8 o;
#pragma unroll
  for (int i = 0; i < 8; i++) {
    union { __hip_bfloat16 b; unsigned short u; } c;
    c.b = __float2bfloat16(s[i]);
    o[i] = c.u;
  }
  return o;
}

// ---------------------------------------------------------------------------
// Prep: build bf16 A=[x|h] (8192x2048), gate-interleaved bf16 W' (4096x2048)
// with W'[4*hh+g][k] = (k<I ? Wx : Wh)[g*H+hh][k'], and bsum[4*hh+g]=bx+bh.
// 8 floats per thread: 2x dwordx4 in, 1x dwordx4 out.
// ---------------------------------------------------------------------------
__global__ __launch_bounds__(256) void prep_kernel(
    const float* __restrict__ x, const float* __restrict__ h,
    const float* __restrict__ Wx, const float* __restrict__ Wh,
    const float* __restrict__ bx, const float* __restrict__ bh,
    __hip_bfloat16* __restrict__ Abf, __hip_bfloat16* __restrict__ Wbf,
    float* __restrict__ bsum) {
  const int idx = blockIdx.x * 256 + threadIdx.x;
  const int ATH = (Bsz * Ksz) / 8;  // 2,097,152 threads for A
  float buf[8];
  if (idx < ATH) {
    const int b = idx >> 8;            // row (2048 elems = 256 chunks/row)
    const int k = (idx & 255) << 3;    // col
    const float* src = (k < Isz) ? (x + (size_t)b * Isz + k)
                                 : (h + (size_t)b * Hsz + (k - Isz));
    *(float4*)(buf)     = ((const float4*)src)[0];
    *(float4*)(buf + 4) = ((const float4*)src)[1];
    *(ushort8*)(Abf + (size_t)b * Ksz + k) = cvt8(buf);
  } else {
    const int t2 = idx - ATH;          // 1,048,576 threads for W'
    const int r = t2 >> 8;             // permuted row 4*hh+g
    const int k = (t2 & 255) << 3;
    const int hh = r >> 2, g = r & 3;
    const float* src = (k < Isz) ? (Wx + (size_t)(g * Hsz + hh) * Isz + k)
                                 : (Wh + (size_t)(g * Hsz + hh) * Hsz + (k - Isz));
    *(float4*)(buf)     = ((const float4*)src)[0];
    *(float4*)(buf + 4) = ((const float4*)src)[1];
    *(ushort8*)(Wbf + (size_t)r * Ksz + k) = cvt8(buf);
  }
  if (idx < Nsz) {
    const int hh = idx >> 2, g = idx & 3;
    bsum[idx] = bx[g * Hsz + hh] + bh[g * Hsz + hh];
  }
}

// ---------------------------------------------------------------------------
// GEMM (A·W'^T) + fused LSTM epilogue.
// m97 structure: 128x128 block tile, BK=32, global_load_lds width=16,
// 4 waves in 2x2, each wave 4x4 grid of 16x16x32 bf16 MFMA.
// C/D layout: col = lane&15, row = (lane>>4)*4 + reg.
// Epilogue: wave-private LDS round-trip -> each lane owns (row, 4 contiguous
// h); float4 c_prev read + float4 c/h stores (full 64B segments per row).
// ---------------------------------------------------------------------------
__global__ __launch_bounds__(256) void lstm_gemm_kernel(
    const __hip_bfloat16* __restrict__ A,   // [8192][2048]
    const __hip_bfloat16* __restrict__ W,   // [4096][2048] gate-interleaved
    const float* __restrict__ bsum,         // [4096] gate-interleaved
    const float* __restrict__ c_prev,       // [8192][1024]
    float* __restrict__ c_out,              // [8192][1024]
    float* __restrict__ h_out) {            // [8192][1024]
  __shared__ __hip_bfloat16 As[BM * BK];  // 8 KB
  __shared__ __hip_bfloat16 Bs[BN * BK];  // 8 KB
  __shared__ float Ew[4][16 * 68];        // 17 KB epilogue exchange, per-wave

  const int tid = threadIdx.x;
  const int lane = tid & 63;
  const int wave = tid >> 6;
  const int wm = wave & 1;
  const int wn = wave >> 1;
  const int row0 = blockIdx.x * BM;
  const int col0 = blockIdx.y * BN;

  const __hip_bfloat16* Ag = A + (size_t)row0 * Ksz;
  const __hip_bfloat16* Wg = W + (size_t)col0 * Ksz;

  // staging: chunk c covers LDS bytes [c*16, c*16+16); row=c>>2, col=(c&3)*8
  const int c0 = tid, c1 = tid + 256;
  const int ar0 = c0 >> 2, ak0 = (c0 & 3) * 8;
  const int ar1 = c1 >> 2, ak1 = (c1 & 3) * 8;

  f32x4 acc[4][4] = {};

  const int q = lane >> 4;    // quad
  const int cl = lane & 15;   // col within 16-wide tile

  for (int kt = 0; kt < Ksz; kt += BK) {
    __syncthreads();  // prior iteration's ds_reads complete before overwrite
    async_copy16(Ag + (size_t)ar0 * Ksz + kt + ak0, (char*)As + c0 * 16);
    async_copy16(Ag + (size_t)ar1 * Ksz + kt + ak1, (char*)As + c1 * 16);
    async_copy16(Wg + (size_t)ar0 * Ksz + kt + ak0, (char*)Bs + c0 * 16);
    async_copy16(Wg + (size_t)ar1 * Ksz + kt + ak1, (char*)Bs + c1 * 16);
    __syncthreads();  // vmcnt(0) drain before s_barrier covers the DMA

    bf16x8 af[4], bfr[4];
#pragma unroll
    for (int i = 0; i < 4; i++)
      af[i] = *(const bf16x8*)(As + (wm * 64 + i * 16 + cl) * BK + q * 8);
#pragma unroll
    for (int j = 0; j < 4; j++)
      bfr[j] = *(const bf16x8*)(Bs + (wn * 64 + j * 16 + cl) * BK + q * 8);
#pragma unroll
    for (int i = 0; i < 4; i++)
#pragma unroll
      for (int j = 0; j < 4; j++)
        acc[i][j] = __builtin_amdgcn_mfma_f32_16x16x32_bf16(af[i], bfr[j],
                                                            acc[i][j], 0, 0, 0);
  }

  // ---- fused LSTM epilogue (LDS round-trip, coalesced I/O) ----
  float bj[4];
#pragma unroll
  for (int j = 0; j < 4; j++)
    bj[j] = bsum[col0 + wn * 64 + j * 16 + cl];

  const int hw = (col0 >> 2) + wn * 16;  // wave's h-window start (16 h values)
  const int r16 = lane >> 2;             // read-phase row 0..15
  const int tt = lane & 3;               // read-phase h-quad 0..3
  float* E = &Ew[wave][0];

#pragma unroll
  for (int i = 0; i < 4; i++) {
    // write phase: lane (q,cl) reg r holds C[q*4+r][j*16+cl] of this 16-row tile
#pragma unroll
    for (int j = 0; j < 4; j++)
#pragma unroll
      for (int r = 0; r < 4; r++)
        E[(q * 4 + r) * 68 + j * 16 + cl] = acc[i][j][r] + bj[j];
    __builtin_amdgcn_wave_barrier();  // keep write->read order (wave-private)
    // read phase: lane owns row r16, h = hw + tt*4 + (0..3); gate cols 4h'+g
    float f[16];
#pragma unroll
    for (int m = 0; m < 4; m++)
      *(float4*)(f + 4 * m) = *(const float4*)(E + r16 * 68 + tt * 16 + 4 * m);

    const int row = row0 + wm * 64 + i * 16 + r16;
    const size_t off = (size_t)row * Hsz + hw + tt * 4;
    const float4 cp4 = *(const float4*)(c_prev + off);
    const float* cpp = (const float*)&cp4;
    float4 c4, h4;
    float* c4p = (float*)&c4;
    float* h4p = (float*)&h4;
#pragma unroll
    for (int u = 0; u < 4; u++) {
      const float ig = sigmoid_f(f[4 * u + 0]);
      const float fg = sigmoid_f(f[4 * u + 1]);
      const float og = sigmoid_f(f[4 * u + 2]);
      const float gg = tanh_f(f[4 * u + 3]);
      const float cn = fg * cpp[u] + ig * gg;
      c4p[u] = cn;
      h4p[u] = og * tanh_f(cn);
    }
    *(float4*)(c_out + off) = c4;
    *(float4*)(h_out + off) = h4;
    __builtin_amdgcn_wave_barrier();  // next i reuses E
  }
}

extern "C" void kernel_launch(void* const* d_in, const int* in_sizes, int n_in,
                              void* d_out, int out_size, void* d_ws,
                              size_t ws_size, hipStream_t stream) {
  (void)in_sizes; (void)n_in; (void)out_size; (void)ws_size;
  const float* x  = (const float*)d_in[0];
  const float* cp = (const float*)d_in[1];
  const float* hp = (const float*)d_in[2];
  const float* Wx = (const float*)d_in[3];
  const float* bx = (const float*)d_in[4];
  const float* Wh = (const float*)d_in[5];
  const float* bh = (const float*)d_in[6];

  __hip_bfloat16* Abf = (__hip_bfloat16*)d_ws;            // 32 MB
  __hip_bfloat16* Wbf = Abf + (size_t)Bsz * Ksz;          // 16 MB
  float* bsum = (float*)(Wbf + (size_t)Nsz * Ksz);        // 16 KB

  float* c_out = (float*)d_out;
  float* h_out = c_out + (size_t)Bsz * Hsz;

  const int total_threads = (Bsz * Ksz) / 8 + (Nsz * Ksz) / 8;  // 3,145,728
  prep_kernel<<<total_threads / 256, 256, 0, stream>>>(x, hp, Wx, Wh, bx, bh,
                                                       Abf, Wbf, bsum);
  dim3 grid(Bsz / BM, Nsz / BN);  // 64 x 32
  lstm_gemm_kernel<<<grid, 256, 0, stream>>>(Abf, Wbf, bsum, cp, c_out, h_out);
}